// Round 14
// baseline (5939.853 us; speedup 1.0000x reference)
//
#include <hip/hip_runtime.h>
#include <hip/hip_bf16.h>

#define B_ 512
#define T_ 256
#define E_ 512
#define H_ 1024
#define K_ 1536

typedef __attribute__((ext_vector_type(4))) float f32x4;
typedef __attribute__((ext_vector_type(8))) short s16x8;
typedef __attribute__((ext_vector_type(4))) unsigned int u32x4;
typedef __attribute__((ext_vector_type(2))) unsigned int u32x2;

typedef unsigned int u32_g __attribute__((address_space(1)));
typedef unsigned int u32_l __attribute__((address_space(3)));

static __device__ __forceinline__ void gload16(const void* g, void* l) {
    __builtin_amdgcn_global_load_lds((const u32_g*)g, (u32_l*)l, 16, 0, 0);
}

static __device__ __forceinline__ short f2b(float f) {
    union { float f; unsigned u; } v; v.f = f;
    unsigned r = v.u + 0x7FFFu + ((v.u >> 16) & 1u);   // RNE
    return (short)(r >> 16);
}
static __device__ __forceinline__ float bf2f(short s) {
    union { unsigned u; float f; } v; v.u = ((unsigned)(unsigned short)s) << 16;
    return v.f;
}
static __device__ __forceinline__ float sigmoidf_(float v) {
    return 1.f / (1.f + expf(-v));
}

#define WAITV(n) asm volatile("s_waitcnt vmcnt(" #n ")" ::: "memory")
#define WAITL    asm volatile("s_waitcnt lgkmcnt(0)" ::: "memory")
#define SB0 __builtin_amdgcn_sched_barrier(0)

// agent-coherent (L3) async loads/stores; pair with WAITV
static __device__ __forceinline__ u32x4 load16sc(const short* p) {
    u32x4 r;
    asm volatile("global_load_dwordx4 %0, %1, off sc1" : "=v"(r) : "v"(p));
    return r;
}
static __device__ __forceinline__ u32x2 load8sc(const short* p) {
    u32x2 r;
    asm volatile("global_load_dwordx2 %0, %1, off sc1" : "=v"(r) : "v"(p));
    return r;
}
static __device__ __forceinline__ void store2sc(const short* p, unsigned v) {
    asm volatile("global_store_short %0, %1, off sc1" :: "v"(p), "v"(v) : "memory");
}

// swizzled fragment read: 128-short rows (16 segs of 16B); logical seg s at
// physical s ^ (row&7)
#define FR(buf, row, k) \
    (*(const s16x8*)&(buf)[(row) * 128 + ((((k) >> 3) ^ ((row) & 7)) << 3)])

// ===========================================================================
// FAST PATH
// ===========================================================================

__global__ __launch_bounds__(256) void prep_fast(
    const float* __restrict__ W_r, const float* __restrict__ W_z,
    const float* __restrict__ W_c, const float* __restrict__ emb,
    short* __restrict__ We, short* __restrict__ Wh, short* __restrict__ embb,
    float* __restrict__ hbuf, short* __restrict__ hb16, unsigned* __restrict__ flags)
{
    const int NW = 3072 * 1536;
    const int NE = 50048 * 512;
    const int NH = 512 * 1024;
    const int NF = 8192;
    const int total = NW + NE + NH + NF;
    for (int idx = blockIdx.x * 256 + threadIdx.x; idx < total; idx += gridDim.x * 256) {
        if (idx < NW) {
            int n = idx / 1536, k = idx - n * 1536;
            const float* W = n < 1024 ? W_r : (n < 2048 ? W_z : W_c);
            float v = W[(size_t)k * 1024 + (n & 1023)];
            if (k < 512) We[(size_t)n * 512 + k] = f2b(v);
            else         Wh[(size_t)n * 1024 + (k - 512)] = f2b(v);
        } else if (idx < NW + NE) {
            int e = idx - NW; int row = e >> 9;
            embb[e] = row < 50000 ? f2b(emb[e]) : (short)0;
        } else if (idx < NW + NE + NH) {
            int h = idx - NW - NE;
            hbuf[h] = 0.f; hb16[h] = 0;
        } else {
            flags[idx - NW - NE - NH] = 0u;
        }
    }
}

__global__ __launch_bounds__(256) void vproj_gemm(
    const short* __restrict__ embb, const short* __restrict__ We,
    short* __restrict__ vp)
{
    __shared__ short As[128 * 64];
    __shared__ short Bs[128 * 64];
    const int tid = threadIdx.x, lane = tid & 63, w = tid >> 6;
    const int wm = (w >> 1) * 64, wn = (w & 1) * 64;
    const int m0 = blockIdx.x * 128, n0 = blockIdx.y * 128;
    f32x4 acc[4][4] = {};
    for (int kc = 0; kc < 8; ++kc) {
        int k0 = kc * 64;
        #pragma unroll
        for (int ii = 0; ii < 4; ++ii) {
            int i = w * 4 + ii;
            int row = i * 8 + (lane >> 3), kk = (lane & 7) * 8;
            gload16(embb + (size_t)(m0 + row) * 512 + k0 + kk, As + i * 512);
            gload16(We   + (size_t)(n0 + row) * 512 + k0 + kk, Bs + i * 512);
        }
        __syncthreads();
        #pragma unroll
        for (int kk = 0; kk < 64; kk += 32) {
            s16x8 a[4], b[4];
            #pragma unroll
            for (int f = 0; f < 4; ++f) {
                a[f] = *(const s16x8*)&As[(wm + f * 16 + (lane & 15)) * 64 + kk + (lane >> 4) * 8];
                b[f] = *(const s16x8*)&Bs[(wn + f * 16 + (lane & 15)) * 64 + kk + (lane >> 4) * 8];
            }
            #pragma unroll
            for (int fm = 0; fm < 4; ++fm)
            #pragma unroll
            for (int fn = 0; fn < 4; ++fn)
                acc[fm][fn] = __builtin_amdgcn_mfma_f32_16x16x32_bf16(a[fm], b[fn], acc[fm][fn], 0, 0, 0);
        }
        __syncthreads();
    }
    #pragma unroll
    for (int fm = 0; fm < 4; ++fm)
    #pragma unroll
    for (int fn = 0; fn < 4; ++fn)
    #pragma unroll
    for (int r = 0; r < 4; ++r) {
        int row = m0 + wm + fm * 16 + (lane >> 4) * 4 + r;
        int col = n0 + wn + fn * 16 + (lane & 15);
        vp[(size_t)row * 3072 + col] = f2b(acc[fm][fn][r]);
    }
}

// group barrier: relaxed agent atomics (sc1 ld/st, no wbl2/inv). WAITV(0)
// drains this wave's sc1 state stores first. First poll check without sleep;
// bounded spin failsafe.
static __device__ __forceinline__ void groupbar2(unsigned* gf, int member, unsigned gen) {
    WAITV(0);
    __syncthreads();
    if (threadIdx.x == 0) {
        __hip_atomic_store(&gf[member * 16], gen,
                           __ATOMIC_RELAXED, __HIP_MEMORY_SCOPE_AGENT);
    }
    if (threadIdx.x < 32) {
        unsigned v = __hip_atomic_load(&gf[threadIdx.x * 16],
                                       __ATOMIC_RELAXED, __HIP_MEMORY_SCOPE_AGENT);
        int spins = 0;
        while (v < gen) {
            __builtin_amdgcn_s_sleep(1);
            v = __hip_atomic_load(&gf[threadIdx.x * 16],
                                  __ATOMIC_RELAXED, __HIP_MEMORY_SCOPE_AGENT);
            if (++spins > (1 << 18)) break;   // failsafe: fail, don't wedge
        }
    }
    __syncthreads();
}

// ---------------------------------------------------------------------------
// one phase of one step. PH=1: rz (A=hb16, B rows = Wr[n*32..]+Wz[1024+n*32..],
// out: r*h -> rh16 (sc1), z -> zL). PH=2: cand (A=rh16, B rows = Wc[2048+n*32..],
// out: h' -> h_reg/hb16/hL).
// Tile: 32 (rows) x (PH==1 ? 64 : 32) cols, K=1024 in 8 chunks of 128.
// A prefetch 4-deep (L3 latency ~1us covered by ~3 iterations of lead);
// B prefetch 2-deep (L2-hot). Static vmcnt ledger, one s_barrier per chunk.
// ---------------------------------------------------------------------------
template<int PH>
static __device__ __forceinline__ void phaseX(
    const short* __restrict__ Ab,    // state rows base (+g*32*1024)
    const short* __restrict__ Wh,
    const short* __restrict__ vp, const int* __restrict__ xidxL,
    int g, int n, int t,
    short* AL, short* BL, short* XpL, float* zL, short* hL,
    const float* br, const float* bz, float bc,   // per-thread hoisted biases
    short* __restrict__ rh16, short* __restrict__ hb16,
    float* __restrict__ hbuf, f32x4& h_reg)
{
    const int tid = threadIdx.x, lane = tid & 63, w = tid >> 6;
    const int wm = (w >> 1) * 16;
    const int wn = (PH == 1) ? (w & 1) * 32 : (w & 1) * 16;
    constexpr int BROWS = (PH == 1) ? 64 : 32;      // B panel rows
    constexpr int BJ    = (PH == 1) ? 4 : 2;        // 16B segs per thread per B chunk
    constexpr int BUFSZ = BROWS * 128;              // shorts per B buffer

    // ---- issue xp gather (oldest in queue; drains under prologue) ----
    u32x4 xp4; u32x2 xp2;
    if constexpr (PH == 1) {
        int row = tid >> 3, part = tid & 7;
        int col = (part < 4) ? (n * 32 + part * 8) : (1024 + n * 32 + (part - 4) * 8);
        xp4 = load16sc(vp + (size_t)xidxL[row] * 3072 + col);
    } else {
        int row = tid >> 3, part = tid & 7;
        xp2 = load8sc(vp + (size_t)xidxL[row] * 3072 + 2048 + n * 32 + part * 4);
    }

    // ---- staging helpers ----
    auto issueA = [&](int c, u32x4* dst) {
        #pragma unroll
        for (int j = 0; j < 2; ++j) {
            int sid = j * 256 + tid, row = sid >> 4, sg = (sid & 15) ^ (row & 7);
            dst[j] = load16sc(Ab + (size_t)row * 1024 + c * 128 + sg * 8);
        }
    };
    auto issueB = [&](int c, int buf) {
        #pragma unroll
        for (int j = 0; j < BJ; ++j) {
            int sid = j * 256 + tid, row = sid >> 4, sg = (sid & 15) ^ (row & 7);
            int grow;
            if constexpr (PH == 1) grow = (row < 32) ? (n * 32 + row) : (1024 + n * 32 + row - 32);
            else                   grow = 2048 + n * 32 + row;
            gload16(Wh + (size_t)grow * 1024 + c * 128 + sg * 8,
                    BL + buf * BUFSZ + (j * 256 + w * 64) * 8);
        }
    };
    auto writeA = [&](int buf, const u32x4* src) {
        #pragma unroll
        for (int j = 0; j < 2; ++j) {
            int sid = j * 256 + tid;
            *(u32x4*)&AL[buf * 4096 + sid * 8] = src[j];
        }
    };

    // ---- prologue: A 4-deep, B 2-deep ----
    u32x4 ra[4][2];
    issueA(0, ra[0]); issueA(1, ra[1]); issueA(2, ra[2]); issueA(3, ra[3]);
    issueB(0, 0); issueB(1, 1);
    // ledger: xp, A0..A3, B0, B1 -> younger than B0 is B1 only
    if constexpr (PH == 1) { WAITV(4); } else { WAITV(2); }   // xp, A0..A3, B0 done
    SB0;
    writeA(0, ra[0]);
    {   // xp regs -> LDS
        int row = tid >> 3, part = tid & 7;
        if constexpr (PH == 1) {
            int dst = (part < 4) ? part * 8 : (32 + (part - 4) * 8);
            *(u32x4*)&XpL[row * 64 + dst] = xp4;
        } else {
            *(u32x2*)&XpL[row * 32 + part * 4] = xp2;
        }
    }
    WAITL;
    __builtin_amdgcn_s_barrier();
    SB0;

    // ---- k-loop: 8 chunks of 128, one barrier per chunk ----
    // iter kc issues A(kc+4) (kc<4) and B(kc+2) (kc<6).
    // Gate at end of iter kc needs A(kc+1) regs (issued >=3 iters ago) and
    // B(kc+1) in LDS (issued 1 iter ago, L2-hot).
    f32x4 acc[2] = {};
    #pragma unroll
    for (int kc = 0; kc < 8; ++kc) {
        if (kc < 4) issueA(kc + 4, ra[kc & 3]);
        if (kc < 6) issueB(kc + 2, (kc + 2) % 3);
        const short* Ac = AL + (kc & 1) * 4096;
        const short* Bc = BL + (kc % 3) * BUFSZ;
        __builtin_amdgcn_s_setprio(1);          // T5: favor MFMA-phase waves
        #pragma unroll
        for (int ks = 0; ks < 4; ++ks) {
            const int kf = ks * 32 + (lane >> 4) * 8;
            s16x8 a = FR(Ac, wm + (lane & 15), kf);
            if constexpr (PH == 1) {
                s16x8 b0 = FR(Bc, wn + (lane & 15), kf);
                s16x8 b1 = FR(Bc, wn + 16 + (lane & 15), kf);
                acc[0] = __builtin_amdgcn_mfma_f32_16x16x32_bf16(a, b0, acc[0], 0, 0, 0);
                acc[1] = __builtin_amdgcn_mfma_f32_16x16x32_bf16(a, b1, acc[1], 0, 0, 0);
            } else {
                s16x8 b0 = FR(Bc, wn + (lane & 15), kf);
                acc[0] = __builtin_amdgcn_mfma_f32_16x16x32_bf16(a, b0, acc[0], 0, 0, 0);
            }
        }
        __builtin_amdgcn_s_setprio(0);
        if (kc < 7) {
            // static ledger: younger-than-B(kc+1) op counts
            if (kc < 4)      { if constexpr (PH == 1) { WAITV(6); } else { WAITV(4); } }
            else if (kc < 6) { if constexpr (PH == 1) { WAITV(4); } else { WAITV(2); } }
            else             { WAITV(0); }
            SB0;
            writeA((kc + 1) & 1, ra[(kc + 1) & 3]);
            WAITL;
            __builtin_amdgcn_s_barrier();
            SB0;
        }
    }

    // ---- epilogue ----
    const int rl0 = wm + (lane >> 4) * 4;
    if constexpr (PH == 1) {
        if ((w & 1) == 0) {   // r waves: global cols n*32 + (fn*16 + lane&15)
            #pragma unroll
            for (int fn = 0; fn < 2; ++fn) {
                int cl = fn * 16 + (lane & 15);
                #pragma unroll
                for (int ri = 0; ri < 4; ++ri) {
                    int rl = rl0 + ri;
                    float v = acc[fn][ri] + bf2f(XpL[rl * 64 + cl]) + br[fn];
                    float rr = sigmoidf_(v);
                    float hv = bf2f(hL[rl * 32 + cl]);
                    store2sc(rh16 + (size_t)(g * 32 + rl) * 1024 + n * 32 + cl,
                             (unsigned)(unsigned short)f2b(rr * hv));
                }
            }
        } else {              // z waves -> zL
            #pragma unroll
            for (int fn = 0; fn < 2; ++fn) {
                int zc = fn * 16 + (lane & 15);
                #pragma unroll
                for (int ri = 0; ri < 4; ++ri) {
                    int rl = rl0 + ri;
                    float v = acc[fn][ri] + bf2f(XpL[rl * 64 + 32 + zc]) + bz[fn];
                    zL[rl * 32 + zc] = sigmoidf_(v);
                }
            }
        }
    } else {
        int cl2 = wn + (lane & 15);
        #pragma unroll
        for (int ri = 0; ri < 4; ++ri) {
            int rl = rl0 + ri;
            float v = acc[0][ri] + bf2f(XpL[rl * 32 + cl2]) + bc;
            float c = tanhf(v);
            float zv = zL[rl * 32 + cl2];
            float h = h_reg[ri];
            float hn = h + zv * (c - h);
            h_reg[ri] = hn;
            short hb = f2b(hn);
            store2sc(hb16 + (size_t)(g * 32 + rl) * 1024 + n * 32 + cl2,
                     (unsigned)(unsigned short)hb);
            hL[rl * 32 + cl2] = hb;
            if (t == T_ - 1)
                hbuf[(size_t)(g * 32 + rl) * 1024 + n * 32 + cl2] = hn;
        }
    }
}

__global__ __launch_bounds__(256, 2) void gru_persistent(
    const int* __restrict__ x, const short* __restrict__ Wh,
    const short* __restrict__ vp,
    const float* __restrict__ b_r, const float* __restrict__ b_z,
    const float* __restrict__ b_c,
    float* __restrict__ hbuf, short* __restrict__ hb16,
    short* __restrict__ rh16, unsigned* __restrict__ flags)
{
    __shared__ short AL[2 * 4096];    // 16 KB  A double-buffer (32x128)
    __shared__ short BL[3 * 8192];    // 48 KB  B triple-buffer (64x128 / 32x128)
    __shared__ short XpL[2048];       // 4 KB   x-projection tile
    __shared__ float zL[1024];        // 4 KB   z (f32), phase1 -> phase2
    __shared__ short hL[1024];        // 2 KB   own h bf16 tile
    __shared__ int xidxL[32];

    const int bid = blockIdx.x;
    const int g = bid >> 5, n = bid & 31;    // 16 groups (32 batch rows) x 32 members
    unsigned* gf = flags + g * 512;

    const int tid = threadIdx.x, lane = tid & 63, w = tid >> 6;
    const int wm = (w >> 1) * 16, wn2 = (w & 1) * 16;

    // hoist per-thread biases
    float br[2], bz[2], bc;
    #pragma unroll
    for (int fn = 0; fn < 2; ++fn) {
        br[fn] = b_r[n * 32 + fn * 16 + (lane & 15)];
        bz[fn] = b_z[n * 32 + fn * 16 + (lane & 15)];
    }
    bc = b_c[n * 32 + wn2 + (lane & 15)];

    // init: h = 0 (regs + own hL tile)
    f32x4 h_reg = {0.f, 0.f, 0.f, 0.f};
    #pragma unroll
    for (int ri = 0; ri < 4; ++ri)
        hL[(wm + (lane >> 4) * 4 + ri) * 32 + wn2 + (lane & 15)] = 0;

    for (int t = 0; t < T_; ++t) {
        if (tid < 32) xidxL[tid] = x[(g * 32 + tid) * T_ + t];
        __syncthreads();
        phaseX<1>(hb16 + (size_t)(g * 32) * 1024, Wh, vp, xidxL, g, n, t,
                  AL, BL, XpL, zL, hL, br, bz, bc, rh16, hb16, hbuf, h_reg);
        groupbar2(gf, n, 2 * t + 1);
        phaseX<2>(rh16 + (size_t)(g * 32) * 1024, Wh, vp, xidxL, g, n, t,
                  AL, BL, XpL, zL, hL, br, bz, bc, rh16, hb16, hbuf, h_reg);
        if (t < T_ - 1) groupbar2(gf, n, 2 * t + 2);
    }
}

__global__ __launch_bounds__(256) void fc_kernel(
    const float* __restrict__ h, const float* __restrict__ Wfc,
    const float* __restrict__ bfc, float* __restrict__ out)
{
    int gw   = (blockIdx.x * 256 + threadIdx.x) >> 6;
    int lane = threadIdx.x & 63;
    if (gw >= B_) return;
    float s = 0.f;
    for (int j = lane; j < H_; j += 64) s += h[(size_t)gw * H_ + j] * Wfc[j];
    #pragma unroll
    for (int off = 32; off; off >>= 1) s += __shfl_down(s, off);
    if (lane == 0) out[gw] = sigmoidf_(s + bfc[0]);
}

// ===========================================================================
// FALLBACK PATH (round-1, used when ws_size is too small)
// ===========================================================================
__global__ __launch_bounds__(256) void prep_fb(
    const float* __restrict__ W_r, const float* __restrict__ W_z,
    const float* __restrict__ W_c,
    short* __restrict__ Wt_rz, short* __restrict__ Wt_c,
    float* __restrict__ hbuf, short* __restrict__ hbf16)
{
    const int PER = H_ * K_;
    int idx = blockIdx.x * 256 + threadIdx.x;
    if (idx < PER * 3) {
        int mm = idx / PER, rem = idx - mm * PER;
        int n = rem / K_, k = rem - n * K_;
        if (mm == 0)      Wt_rz[(size_t)n * K_ + k]        = f2b(W_r[(size_t)k * H_ + n]);
        else if (mm == 1) Wt_rz[(size_t)(H_ + n) * K_ + k] = f2b(W_z[(size_t)k * H_ + n]);
        else              Wt_c[(size_t)n * K_ + k]         = f2b(W_c[(size_t)k * H_ + n]);
    }
    if (idx < B_ * H_) { hbuf[idx] = 0.f; hbf16[idx] = 0; }
}

template<int MODE>
__global__ __launch_bounds__(256) void gru_gemm(
    const int* __restrict__ x, const float* __restrict__ emb,
    const short* __restrict__ Wt, const short* __restrict__ hpart,
    const float* __restrict__ bias0, const float* __restrict__ bias1,
    const float* __restrict__ hbuf, float* __restrict__ zbuf,
    short* __restrict__ rh_out, float* __restrict__ h_out,
    short* __restrict__ hb_out, int t)
{
    __shared__ short As2[64][72];
    __shared__ short Bs2[64][72];
    __shared__ int xidx2[64];
    const int tid = threadIdx.x;
    const int bm = blockIdx.x, bn = blockIdx.y;
    if (tid < 64) xidx2[tid] = x[(bm * 64 + tid) * T_ + t];
    f32x4 acc[2][2] = {};
    const int m  = tid >> 2;
    const int ks = (tid & 3) * 16;
    const int w  = tid >> 6, lane = tid & 63;
    const int wm = (w >> 1) * 32, wn = (w & 1) * 32;
    const int lr = lane & 15, lk = (lane >> 4) * 8;
    __syncthreads();
    for (int kt = 0; kt < 24; ++kt) {
        const int k0 = kt * 64;
        if (k0 < E_) {
            const int row = xidx2[m];
            const float4* src = (const float4*)&emb[(size_t)row * E_ + k0 + ks];
            short tmp[16];
            #pragma unroll
            for (int v = 0; v < 4; ++v) {
                float4 f = src[v];
                tmp[v*4+0] = f2b(f.x); tmp[v*4+1] = f2b(f.y);
                tmp[v*4+2] = f2b(f.z); tmp[v*4+3] = f2b(f.w);
            }
            *(s16x8*)&As2[m][ks]     = *(const s16x8*)&tmp[0];
            *(s16x8*)&As2[m][ks + 8] = *(const s16x8*)&tmp[8];
        } else {
            const s16x8* src = (const s16x8*)&hpart[(size_t)(bm*64 + m) * H_ + (k0 - E_ + ks)];
            *(s16x8*)&As2[m][ks]     = src[0];
            *(s16x8*)&As2[m][ks + 8] = src[1];
        }
        {
            const s16x8* src = (const s16x8*)&Wt[(size_t)(bn*64 + m) * K_ + k0 + ks];
            *(s16x8*)&Bs2[m][ks]     = src[0];
            *(s16x8*)&Bs2[m][ks + 8] = src[1];
        }
        __syncthreads();
        #pragma unroll
        for (int kk = 0; kk < 64; kk += 32) {
            s16x8 a0 = *(const s16x8*)&As2[wm      + lr][kk + lk];
            s16x8 a1 = *(const s16x8*)&As2[wm + 16 + lr][kk + lk];
            s16x8 b0 = *(const s16x8*)&Bs2[wn      + lr][kk + lk];
            s16x8 b1 = *(const s16x8*)&Bs2[wn + 16 + lr][kk + lk];
            acc[0][0] = __builtin_amdgcn_mfma_f32_16x16x32_bf16(a0, b0, acc[0][0], 0, 0, 0);
            acc[0][1] = __builtin_amdgcn_mfma_f32_16x16x32_bf16(a0, b1, acc[0][1], 0, 0, 0);
            acc[1][0] = __builtin_amdgcn_mfma_f32_16x16x32_bf16(a1, b0, acc[1][0], 0, 0, 0);
            acc[1][1] = __builtin_amdgcn_mfma_f32_16x16x32_bf16(a1, b1, acc[1][1], 0, 0, 0);
        }
        __syncthreads();
    }
    #pragma unroll
    for (int fm = 0; fm < 2; ++fm)
    #pragma unroll
    for (int fn = 0; fn < 2; ++fn)
    #pragma unroll
    for (int r = 0; r < 4; ++r) {
        const int row = bm * 64 + wm + fm * 16 + ((lane >> 4) * 4 + r);
        const int n   = bn * 64 + wn + fn * 16 + (lane & 15);
        float v = acc[fm][fn][r];
        if (MODE == 0) {
            if (n < H_) {
                float rr = sigmoidf_(v + bias0[n]);
                size_t idx = (size_t)row * H_ + n;
                rh_out[idx] = f2b(rr * hbuf[idx]);
            } else {
                int nz = n - H_;
                zbuf[(size_t)row * H_ + nz] = sigmoidf_(v + bias1[nz]);
            }
        } else {
            float ht = tanhf(v + bias0[n]);
            size_t idx = (size_t)row * H_ + n;
            float h = hbuf[idx], z = zbuf[idx];
            float hn = (1.f - z) * h + z * ht;
            h_out[idx]  = hn;
            hb_out[idx] = f2b(hn);
        }
    }
}

// ===========================================================================
extern "C" void kernel_launch(void* const* d_in, const int* in_sizes, int n_in,
                              void* d_out, int out_size, void* d_ws, size_t ws_size,
                              hipStream_t stream) {
    const int*   x    = (const int*)  d_in[0];
    const float* emb  = (const float*)d_in[1];
    const float* W_r  = (const float*)d_in[2];
    const float* b_r  = (const float*)d_in[3];
    const float* W_z  = (const float*)d_in[4];
    const float* b_z  = (const float*)d_in[5];
    const float* W_c  = (const float*)d_in[6];
    const float* b_c  = (const float*)d_in[7];
    const float* W_fc = (const float*)d_in[8];
    const float* b_fc = (const float*)d_in[9];

    char* ws = (char*)d_ws;
    const size_t NEED = 374489088ULL;

    if (ws_size >= NEED) {
        short*    We    = (short*)(ws);
        short*    Wh    = (short*)(ws + 3145728);
        short*    embb  = (short*)(ws + 9437184);
        short*    vp    = (short*)(ws + 60686336);
        float*    hbuf  = (float*)(ws + 368181248);
        short*    hb16  = (short*)(ws + 370278400);
        short*    rh16  = (short*)(ws + 371326976);
        unsigned* flags = (unsigned*)(ws + 372375552);

        prep_fast<<<2048, 256, 0, stream>>>(W_r, W_z, W_c, emb, We, Wh, embb, hbuf, hb16, flags);
        vproj_gemm<<<dim3(391, 24), 256, 0, stream>>>(embb, We, vp);
        gru_persistent<<<512, 256, 0, stream>>>(x, Wh, vp, b_r, b_z, b_c,
                                                hbuf, hb16, rh16, flags);
        fc_kernel<<<128, 256, 0, stream>>>(hbuf, W_fc, b_fc, (float*)d_out);
    } else {
        short* Wt_rz  = (short*)(ws);
        short* Wt_c   = (short*)(ws + 6291456);
        float* hbuf   = (float*)(ws + 9437184);
        short* hbf16  = (short*)(ws + 11534336);
        short* rhbf16 = (short*)(ws + 12582912);
        float* zbuf   = (float*)(ws + 13631488);

        prep_fb<<<18432, 256, 0, stream>>>(W_r, W_z, W_c, Wt_rz, Wt_c, hbuf, hbf16);
        for (int t = 0; t < T_; ++t) {
            gru_gemm<0><<<dim3(8, 32), 256, 0, stream>>>(
                x, emb, Wt_rz, hbf16, b_r, b_z, hbuf, zbuf, rhbf16, nullptr, nullptr, t);
            gru_gemm<1><<<dim3(8, 16), 256, 0, stream>>>(
                x, emb, Wt_c, rhbf16, b_c, nullptr, hbuf, zbuf, nullptr, hbuf, hbf16, t);
        }
        fc_kernel<<<128, 256, 0, stream>>>(hbuf, W_fc, b_fc, (float*)d_out);
    }
}

// Round 15
// 5273.453 us; speedup vs baseline: 1.1264x; 1.1264x over previous
//
#include <hip/hip_runtime.h>
#include <hip/hip_bf16.h>

#define B_ 512
#define T_ 256
#define E_ 512
#define H_ 1024
#define K_ 1536

typedef __attribute__((ext_vector_type(4))) float f32x4;
typedef __attribute__((ext_vector_type(8))) short s16x8;
typedef __attribute__((ext_vector_type(4))) unsigned int u32x4;
typedef __attribute__((ext_vector_type(2))) unsigned int u32x2;

typedef unsigned int u32_g __attribute__((address_space(1)));
typedef unsigned int u32_l __attribute__((address_space(3)));

static __device__ __forceinline__ void gload16(const void* g, void* l) {
    __builtin_amdgcn_global_load_lds((const u32_g*)g, (u32_l*)l, 16, 0, 0);
}
// coherent variant: aux=16 == CPol SC1 on gfx940/950 (agent-scope, L3)
static __device__ __forceinline__ void gload16sc(const void* g, void* l) {
    __builtin_amdgcn_global_load_lds((const u32_g*)g, (u32_l*)l, 16, 0, 16);
}

static __device__ __forceinline__ short f2b(float f) {
    union { float f; unsigned u; } v; v.f = f;
    unsigned r = v.u + 0x7FFFu + ((v.u >> 16) & 1u);   // RNE
    return (short)(r >> 16);
}
static __device__ __forceinline__ float bf2f(short s) {
    union { unsigned u; float f; } v; v.u = ((unsigned)(unsigned short)s) << 16;
    return v.f;
}
static __device__ __forceinline__ float sigmoidf_(float v) {
    return 1.f / (1.f + expf(-v));
}

#define WAITV(n) asm volatile("s_waitcnt vmcnt(" #n ")" ::: "memory")
#define WAITL    asm volatile("s_waitcnt lgkmcnt(0)" ::: "memory")
#define SB0 __builtin_amdgcn_sched_barrier(0)

// agent-coherent (L3) async loads/stores; pair with WAITV
static __device__ __forceinline__ u32x4 load16sc(const short* p) {
    u32x4 r;
    asm volatile("global_load_dwordx4 %0, %1, off sc1" : "=v"(r) : "v"(p));
    return r;
}
static __device__ __forceinline__ u32x2 load8sc(const short* p) {
    u32x2 r;
    asm volatile("global_load_dwordx2 %0, %1, off sc1" : "=v"(r) : "v"(p));
    return r;
}
static __device__ __forceinline__ void store2sc(const short* p, unsigned v) {
    asm volatile("global_store_short %0, %1, off sc1" :: "v"(p), "v"(v) : "memory");
}

// swizzled fragment read: 128-short rows (16 segs of 16B); logical seg s at
// physical s ^ (row&7)
#define FR(buf, row, k) \
    (*(const s16x8*)&(buf)[(row) * 128 + ((((k) >> 3) ^ ((row) & 7)) << 3)])

// ===========================================================================
// FAST PATH
// ===========================================================================

__global__ __launch_bounds__(256) void prep_fast(
    const float* __restrict__ W_r, const float* __restrict__ W_z,
    const float* __restrict__ W_c, const float* __restrict__ emb,
    short* __restrict__ We, short* __restrict__ Wh, short* __restrict__ embb,
    float* __restrict__ hbuf, short* __restrict__ hb16, unsigned* __restrict__ flags)
{
    const int NW = 3072 * 1536;
    const int NE = 50048 * 512;
    const int NH = 512 * 1024;
    const int NF = 8192;
    const int total = NW + NE + NH + NF;
    for (int idx = blockIdx.x * 256 + threadIdx.x; idx < total; idx += gridDim.x * 256) {
        if (idx < NW) {
            int n = idx / 1536, k = idx - n * 1536;
            const float* W = n < 1024 ? W_r : (n < 2048 ? W_z : W_c);
            float v = W[(size_t)k * 1024 + (n & 1023)];
            if (k < 512) We[(size_t)n * 512 + k] = f2b(v);
            else         Wh[(size_t)n * 1024 + (k - 512)] = f2b(v);
        } else if (idx < NW + NE) {
            int e = idx - NW; int row = e >> 9;
            embb[e] = row < 50000 ? f2b(emb[e]) : (short)0;
        } else if (idx < NW + NE + NH) {
            int h = idx - NW - NE;
            hbuf[h] = 0.f; hb16[h] = 0;
        } else {
            flags[idx - NW - NE - NH] = 0u;
        }
    }
}

__global__ __launch_bounds__(256) void vproj_gemm(
    const short* __restrict__ embb, const short* __restrict__ We,
    short* __restrict__ vp)
{
    __shared__ short As[128 * 64];
    __shared__ short Bs[128 * 64];
    const int tid = threadIdx.x, lane = tid & 63, w = tid >> 6;
    const int wm = (w >> 1) * 64, wn = (w & 1) * 64;
    const int m0 = blockIdx.x * 128, n0 = blockIdx.y * 128;
    f32x4 acc[4][4] = {};
    for (int kc = 0; kc < 8; ++kc) {
        int k0 = kc * 64;
        #pragma unroll
        for (int ii = 0; ii < 4; ++ii) {
            int i = w * 4 + ii;
            int row = i * 8 + (lane >> 3), kk = (lane & 7) * 8;
            gload16(embb + (size_t)(m0 + row) * 512 + k0 + kk, As + i * 512);
            gload16(We   + (size_t)(n0 + row) * 512 + k0 + kk, Bs + i * 512);
        }
        __syncthreads();
        #pragma unroll
        for (int kk = 0; kk < 64; kk += 32) {
            s16x8 a[4], b[4];
            #pragma unroll
            for (int f = 0; f < 4; ++f) {
                a[f] = *(const s16x8*)&As[(wm + f * 16 + (lane & 15)) * 64 + kk + (lane >> 4) * 8];
                b[f] = *(const s16x8*)&Bs[(wn + f * 16 + (lane & 15)) * 64 + kk + (lane >> 4) * 8];
            }
            #pragma unroll
            for (int fm = 0; fm < 4; ++fm)
            #pragma unroll
            for (int fn = 0; fn < 4; ++fn)
                acc[fm][fn] = __builtin_amdgcn_mfma_f32_16x16x32_bf16(a[fm], b[fn], acc[fm][fn], 0, 0, 0);
        }
        __syncthreads();
    }
    #pragma unroll
    for (int fm = 0; fm < 4; ++fm)
    #pragma unroll
    for (int fn = 0; fn < 4; ++fn)
    #pragma unroll
    for (int r = 0; r < 4; ++r) {
        int row = m0 + wm + fm * 16 + (lane >> 4) * 4 + r;
        int col = n0 + wn + fn * 16 + (lane & 15);
        vp[(size_t)row * 3072 + col] = f2b(acc[fm][fn][r]);
    }
}

// group barrier: relaxed agent atomics (sc1 ld/st, no wbl2/inv). WAITV(0)
// drains this wave's sc1 state stores first. First poll check without sleep;
// bounded spin failsafe.
static __device__ __forceinline__ void groupbar2(unsigned* gf, int member, unsigned gen) {
    WAITV(0);
    __syncthreads();
    if (threadIdx.x == 0) {
        __hip_atomic_store(&gf[member * 16], gen,
                           __ATOMIC_RELAXED, __HIP_MEMORY_SCOPE_AGENT);
    }
    if (threadIdx.x < 32) {
        unsigned v = __hip_atomic_load(&gf[threadIdx.x * 16],
                                       __ATOMIC_RELAXED, __HIP_MEMORY_SCOPE_AGENT);
        int spins = 0;
        while (v < gen) {
            __builtin_amdgcn_s_sleep(1);
            v = __hip_atomic_load(&gf[threadIdx.x * 16],
                                  __ATOMIC_RELAXED, __HIP_MEMORY_SCOPE_AGENT);
            if (++spins > (1 << 18)) break;   // failsafe: fail, don't wedge
        }
    }
    __syncthreads();
}

// ---------------------------------------------------------------------------
// one phase of one step. PH=1: rz (A=hb16, B rows = Wr[n*32..]+Wz[1024+n*32..],
// out: r*h -> rh16 (sc1), z -> zL). PH=2: cand (A=rh16, B rows = Wc[2048+n*32..],
// out: h' -> h_reg/hb16/hL).
// Tile: 32 (rows) x (PH==1 ? 64 : 32) cols, K=1024 in 8 chunks of 128.
// BOTH operands staged via global_load_lds (A with aux=16 = SC1 coherent).
// A triple-buffered (2-ahead issue), B double-buffered (1-ahead, L2-hot).
// No in-loop LDS writes -> no lgkm waits; one s_barrier per chunk.
// ---------------------------------------------------------------------------
template<int PH>
static __device__ __forceinline__ void phaseX(
    const short* __restrict__ Ab,    // state rows base (+g*32*1024)
    const short* __restrict__ Wh,
    const short* __restrict__ vp, const int* __restrict__ xidxL,
    int g, int n, int t,
    short* AL, short* BL, short* XpL, float* zL, short* hL,
    const float* br, const float* bz, float bc,   // per-thread hoisted biases
    short* __restrict__ rh16, short* __restrict__ hb16,
    float* __restrict__ hbuf, f32x4& h_reg)
{
    const int tid = threadIdx.x, lane = tid & 63, w = tid >> 6;
    const int wm = (w >> 1) * 16;
    const int wn = (PH == 1) ? (w & 1) * 32 : (w & 1) * 16;
    constexpr int BROWS = (PH == 1) ? 64 : 32;      // B panel rows
    constexpr int BJ    = (PH == 1) ? 4 : 2;        // 16B segs per thread per B chunk
    constexpr int BUFSZ = BROWS * 128;              // shorts per B buffer

    // ---- issue xp gather (oldest in queue; drains under prologue) ----
    u32x4 xp4; u32x2 xp2;
    if constexpr (PH == 1) {
        int row = tid >> 3, part = tid & 7;
        int col = (part < 4) ? (n * 32 + part * 8) : (1024 + n * 32 + (part - 4) * 8);
        xp4 = load16sc(vp + (size_t)xidxL[row] * 3072 + col);
    } else {
        int row = tid >> 3, part = tid & 7;
        xp2 = load8sc(vp + (size_t)xidxL[row] * 3072 + 2048 + n * 32 + part * 4);
    }

    // ---- staging helpers (both direct-to-LDS) ----
    auto issueA = [&](int c, int buf) {   // coherent (sc1) A chunk: 2 gloads
        #pragma unroll
        for (int j = 0; j < 2; ++j) {
            int sid = j * 256 + tid, row = sid >> 4, sg = (sid & 15) ^ (row & 7);
            gload16sc(Ab + (size_t)row * 1024 + c * 128 + sg * 8,
                      AL + buf * 4096 + (j * 256 + w * 64) * 8);
        }
    };
    auto issueB = [&](int c, int buf) {   // plain (L2-hot) B chunk
        #pragma unroll
        for (int j = 0; j < BJ; ++j) {
            int sid = j * 256 + tid, row = sid >> 4, sg = (sid & 15) ^ (row & 7);
            int grow;
            if constexpr (PH == 1) grow = (row < 32) ? (n * 32 + row) : (1024 + n * 32 + row - 32);
            else                   grow = 2048 + n * 32 + row;
            gload16(Wh + (size_t)grow * 1024 + c * 128 + sg * 8,
                    BL + buf * BUFSZ + (j * 256 + w * 64) * 8);
        }
    };

    // ---- prologue: B0 (1-ahead baseline), A0+A1 (2-ahead) ----
    issueB(0, 0);
    issueA(0, 0);
    issueA(1, 1);
    WAITV(2);   // xp, B0, A0 done; A1 outstanding
    SB0;
    {   // xp regs -> LDS
        int row = tid >> 3, part = tid & 7;
        if constexpr (PH == 1) {
            int dst = (part < 4) ? part * 8 : (32 + (part - 4) * 8);
            *(u32x4*)&XpL[row * 64 + dst] = xp4;
        } else {
            *(u32x2*)&XpL[row * 32 + part * 4] = xp2;
        }
    }
    WAITL;
    __builtin_amdgcn_s_barrier();
    SB0;

    // ---- k-loop: 8 chunks of 128; issue B(kc+1) then A(kc+2); gate WAITV(2) ----
    f32x4 acc[2] = {};
    #pragma unroll
    for (int kc = 0; kc < 8; ++kc) {
        if (kc < 7) issueB(kc + 1, (kc + 1) & 1);
        if (kc < 6) issueA(kc + 2, (kc + 2) % 3);
        const short* Ac = AL + (kc % 3) * 4096;
        const short* Bc = BL + (kc & 1) * BUFSZ;
        __builtin_amdgcn_s_setprio(1);          // T5: favor MFMA-phase waves
        #pragma unroll
        for (int ks = 0; ks < 4; ++ks) {
            const int kf = ks * 32 + (lane >> 4) * 8;
            s16x8 a = FR(Ac, wm + (lane & 15), kf);
            if constexpr (PH == 1) {
                s16x8 b0 = FR(Bc, wn + (lane & 15), kf);
                s16x8 b1 = FR(Bc, wn + 16 + (lane & 15), kf);
                acc[0] = __builtin_amdgcn_mfma_f32_16x16x32_bf16(a, b0, acc[0], 0, 0, 0);
                acc[1] = __builtin_amdgcn_mfma_f32_16x16x32_bf16(a, b1, acc[1], 0, 0, 0);
            } else {
                s16x8 b0 = FR(Bc, wn + (lane & 15), kf);
                acc[0] = __builtin_amdgcn_mfma_f32_16x16x32_bf16(a, b0, acc[0], 0, 0, 0);
            }
        }
        __builtin_amdgcn_s_setprio(0);
        if (kc < 7) {
            // need B(kc+1)+A(kc+1) landed; A(kc+2) (2 loads) may stay in flight
            if (kc < 6) { WAITV(2); } else { WAITV(0); }
            SB0;
            __builtin_amdgcn_s_barrier();
            SB0;
        }
    }

    // ---- epilogue ----
    const int rl0 = wm + (lane >> 4) * 4;
    if constexpr (PH == 1) {
        if ((w & 1) == 0) {   // r waves: global cols n*32 + (fn*16 + lane&15)
            #pragma unroll
            for (int fn = 0; fn < 2; ++fn) {
                int cl = fn * 16 + (lane & 15);
                #pragma unroll
                for (int ri = 0; ri < 4; ++ri) {
                    int rl = rl0 + ri;
                    float v = acc[fn][ri] + bf2f(XpL[rl * 64 + cl]) + br[fn];
                    float rr = sigmoidf_(v);
                    float hv = bf2f(hL[rl * 32 + cl]);
                    store2sc(rh16 + (size_t)(g * 32 + rl) * 1024 + n * 32 + cl,
                             (unsigned)(unsigned short)f2b(rr * hv));
                }
            }
        } else {              // z waves -> zL
            #pragma unroll
            for (int fn = 0; fn < 2; ++fn) {
                int zc = fn * 16 + (lane & 15);
                #pragma unroll
                for (int ri = 0; ri < 4; ++ri) {
                    int rl = rl0 + ri;
                    float v = acc[fn][ri] + bf2f(XpL[rl * 64 + 32 + zc]) + bz[fn];
                    zL[rl * 32 + zc] = sigmoidf_(v);
                }
            }
        }
    } else {
        int cl2 = wn + (lane & 15);
        #pragma unroll
        for (int ri = 0; ri < 4; ++ri) {
            int rl = rl0 + ri;
            float v = acc[0][ri] + bf2f(XpL[rl * 32 + cl2]) + bc;
            float c = tanhf(v);
            float zv = zL[rl * 32 + cl2];
            float h = h_reg[ri];
            float hn = h + zv * (c - h);
            h_reg[ri] = hn;
            short hb = f2b(hn);
            store2sc(hb16 + (size_t)(g * 32 + rl) * 1024 + n * 32 + cl2,
                     (unsigned)(unsigned short)hb);
            hL[rl * 32 + cl2] = hb;
            if (t == T_ - 1)
                hbuf[(size_t)(g * 32 + rl) * 1024 + n * 32 + cl2] = hn;
        }
    }
}

__global__ __launch_bounds__(256, 2) void gru_persistent(
    const int* __restrict__ x, const short* __restrict__ Wh,
    const short* __restrict__ vp,
    const float* __restrict__ b_r, const float* __restrict__ b_z,
    const float* __restrict__ b_c,
    float* __restrict__ hbuf, short* __restrict__ hb16,
    short* __restrict__ rh16, unsigned* __restrict__ flags)
{
    __shared__ short AL[3 * 4096];    // 24 KB  A triple-buffer (32x128)
    __shared__ short BL[2 * 8192];    // 32 KB  B double-buffer (64x128 / 32x128)
    __shared__ short XpL[2048];       // 4 KB   x-projection tile
    __shared__ float zL[1024];        // 4 KB   z (f32), phase1 -> phase2
    __shared__ short hL[1024];        // 2 KB   own h bf16 tile
    __shared__ int xidxL[32];

    const int bid = blockIdx.x;
    const int g = bid >> 5, n = bid & 31;    // 16 groups (32 batch rows) x 32 members
    unsigned* gf = flags + g * 512;

    const int tid = threadIdx.x, lane = tid & 63, w = tid >> 6;
    const int wm = (w >> 1) * 16, wn2 = (w & 1) * 16;

    // hoist per-thread biases
    float br[2], bz[2], bc;
    #pragma unroll
    for (int fn = 0; fn < 2; ++fn) {
        br[fn] = b_r[n * 32 + fn * 16 + (lane & 15)];
        bz[fn] = b_z[n * 32 + fn * 16 + (lane & 15)];
    }
    bc = b_c[n * 32 + wn2 + (lane & 15)];

    // init: h = 0 (regs + own hL tile)
    f32x4 h_reg = {0.f, 0.f, 0.f, 0.f};
    #pragma unroll
    for (int ri = 0; ri < 4; ++ri)
        hL[(wm + (lane >> 4) * 4 + ri) * 32 + wn2 + (lane & 15)] = 0;

    for (int t = 0; t < T_; ++t) {
        if (tid < 32) xidxL[tid] = x[(g * 32 + tid) * T_ + t];
        __syncthreads();
        phaseX<1>(hb16 + (size_t)(g * 32) * 1024, Wh, vp, xidxL, g, n, t,
                  AL, BL, XpL, zL, hL, br, bz, bc, rh16, hb16, hbuf, h_reg);
        groupbar2(gf, n, 2 * t + 1);
        phaseX<2>(rh16 + (size_t)(g * 32) * 1024, Wh, vp, xidxL, g, n, t,
                  AL, BL, XpL, zL, hL, br, bz, bc, rh16, hb16, hbuf, h_reg);
        if (t < T_ - 1) groupbar2(gf, n, 2 * t + 2);
    }
}

__global__ __launch_bounds__(256) void fc_kernel(
    const float* __restrict__ h, const float* __restrict__ Wfc,
    const float* __restrict__ bfc, float* __restrict__ out)
{
    int gw   = (blockIdx.x * 256 + threadIdx.x) >> 6;
    int lane = threadIdx.x & 63;
    if (gw >= B_) return;
    float s = 0.f;
    for (int j = lane; j < H_; j += 64) s += h[(size_t)gw * H_ + j] * Wfc[j];
    #pragma unroll
    for (int off = 32; off; off >>= 1) s += __shfl_down(s, off);
    if (lane == 0) out[gw] = sigmoidf_(s + bfc[0]);
}

// ===========================================================================
// FALLBACK PATH (round-1, used when ws_size is too small)
// ===========================================================================
__global__ __launch_bounds__(256) void prep_fb(
    const float* __restrict__ W_r, const float* __restrict__ W_z,
    const float* __restrict__ W_c,
    short* __restrict__ Wt_rz, short* __restrict__ Wt_c,
    float* __restrict__ hbuf, short* __restrict__ hbf16)
{
    const int PER = H_ * K_;
    int idx = blockIdx.x * 256 + threadIdx.x;
    if (idx < PER * 3) {
        int mm = idx / PER, rem = idx - mm * PER;
        int n = rem / K_, k = rem - n * K_;
        if (mm == 0)      Wt_rz[(size_t)n * K_ + k]        = f2b(W_r[(size_t)k * H_ + n]);
        else if (mm == 1) Wt_rz[(size_t)(H_ + n) * K_ + k] = f2b(W_z[(size_t)k * H_ + n]);
        else              Wt_c[(size_t)n * K_ + k]         = f2b(W_c[(size_t)k * H_ + n]);
    }
    if (idx < B_ * H_) { hbuf[idx] = 0.f; hbf16[idx] = 0; }
}

template<int MODE>
__global__ __launch_bounds__(256) void gru_gemm(
    const int* __restrict__ x, const float* __restrict__ emb,
    const short* __restrict__ Wt, const short* __restrict__ hpart,
    const float* __restrict__ bias0, const float* __restrict__ bias1,
    const float* __restrict__ hbuf, float* __restrict__ zbuf,
    short* __restrict__ rh_out, float* __restrict__ h_out,
    short* __restrict__ hb_out, int t)
{
    __shared__ short As2[64][72];
    __shared__ short Bs2[64][72];
    __shared__ int xidx2[64];
    const int tid = threadIdx.x;
    const int bm = blockIdx.x, bn = blockIdx.y;
    if (tid < 64) xidx2[tid] = x[(bm * 64 + tid) * T_ + t];
    f32x4 acc[2][2] = {};
    const int m  = tid >> 2;
    const int ks = (tid & 3) * 16;
    const int w  = tid >> 6, lane = tid & 63;
    const int wm = (w >> 1) * 32, wn = (w & 1) * 32;
    const int lr = lane & 15, lk = (lane >> 4) * 8;
    __syncthreads();
    for (int kt = 0; kt < 24; ++kt) {
        const int k0 = kt * 64;
        if (k0 < E_) {
            const int row = xidx2[m];
            const float4* src = (const float4*)&emb[(size_t)row * E_ + k0 + ks];
            short tmp[16];
            #pragma unroll
            for (int v = 0; v < 4; ++v) {
                float4 f = src[v];
                tmp[v*4+0] = f2b(f.x); tmp[v*4+1] = f2b(f.y);
                tmp[v*4+2] = f2b(f.z); tmp[v*4+3] = f2b(f.w);
            }
            *(s16x8*)&As2[m][ks]     = *(const s16x8*)&tmp[0];
            *(s16x8*)&As2[m][ks + 8] = *(const s16x8*)&tmp[8];
        } else {
            const s16x8* src = (const s16x8*)&hpart[(size_t)(bm*64 + m) * H_ + (k0 - E_ + ks)];
            *(s16x8*)&As2[m][ks]     = src[0];
            *(s16x8*)&As2[m][ks + 8] = src[1];
        }
        {
            const s16x8* src = (const s16x8*)&Wt[(size_t)(bn*64 + m) * K_ + k0 + ks];
            *(s16x8*)&Bs2[m][ks]     = src[0];
            *(s16x8*)&Bs2[m][ks + 8] = src[1];
        }
        __syncthreads();
        #pragma unroll
        for (int kk = 0; kk < 64; kk += 32) {
            s16x8 a0 = *(const s16x8*)&As2[wm      + lr][kk + lk];
            s16x8 a1 = *(const s16x8*)&As2[wm + 16 + lr][kk + lk];
            s16x8 b0 = *(const s16x8*)&Bs2[wn      + lr][kk + lk];
            s16x8 b1 = *(const s16x8*)&Bs2[wn + 16 + lr][kk + lk];
            acc[0][0] = __builtin_amdgcn_mfma_f32_16x16x32_bf16(a0, b0, acc[0][0], 0, 0, 0);
            acc[0][1] = __builtin_amdgcn_mfma_f32_16x16x32_bf16(a0, b1, acc[0][1], 0, 0, 0);
            acc[1][0] = __builtin_amdgcn_mfma_f32_16x16x32_bf16(a1, b0, acc[1][0], 0, 0, 0);
            acc[1][1] = __builtin_amdgcn_mfma_f32_16x16x32_bf16(a1, b1, acc[1][1], 0, 0, 0);
        }
        __syncthreads();
    }
    #pragma unroll
    for (int fm = 0; fm < 2; ++fm)
    #pragma unroll
    for (int fn = 0; fn < 2; ++fn)
    #pragma unroll
    for (int r = 0; r < 4; ++r) {
        const int row = bm * 64 + wm + fm * 16 + ((lane >> 4) * 4 + r);
        const int n   = bn * 64 + wn + fn * 16 + (lane & 15);
        float v = acc[fm][fn][r];
        if (MODE == 0) {
            if (n < H_) {
                float rr = sigmoidf_(v + bias0[n]);
                size_t idx = (size_t)row * H_ + n;
                rh_out[idx] = f2b(rr * hbuf[idx]);
            } else {
                int nz = n - H_;
                zbuf[(size_t)row * H_ + nz] = sigmoidf_(v + bias1[nz]);
            }
        } else {
            float ht = tanhf(v + bias0[n]);
            size_t idx = (size_t)row * H_ + n;
            float h = hbuf[idx], z = zbuf[idx];
            float hn = (1.f - z) * h + z * ht;
            h_out[idx]  = hn;
            hb_out[idx] = f2b(hn);
        }
    }
}

// ===========================================================================
extern "C" void kernel_launch(void* const* d_in, const int* in_sizes, int n_in,
                              void* d_out, int out_size, void* d_ws, size_t ws_size,
                              hipStream_t stream) {
    const int*   x    = (const int*)  d_in[0];
    const float* emb  = (const float*)d_in[1];
    const float* W_r  = (const float*)d_in[2];
    const float* b_r  = (const float*)d_in[3];
    const float* W_z  = (const float*)d_in[4];
    const float* b_z  = (const float*)d_in[5];
    const float* W_c  = (const float*)d_in[6];
    const float* b_c  = (const float*)d_in[7];
    const float* W_fc = (const float*)d_in[8];
    const float* b_fc = (const float*)d_in[9];

    char* ws = (char*)d_ws;
    const size_t NEED = 374489088ULL;

    if (ws_size >= NEED) {
        short*    We    = (short*)(ws);
        short*    Wh    = (short*)(ws + 3145728);
        short*    embb  = (short*)(ws + 9437184);
        short*    vp    = (short*)(ws + 60686336);
        float*    hbuf  = (float*)(ws + 368181248);
        short*    hb16  = (short*)(ws + 370278400);
        short*    rh16  = (short*)(ws + 371326976);
        unsigned* flags = (unsigned*)(ws + 372375552);

        prep_fast<<<2048, 256, 0, stream>>>(W_r, W_z, W_c, emb, We, Wh, embb, hbuf, hb16, flags);
        vproj_gemm<<<dim3(391, 24), 256, 0, stream>>>(embb, We, vp);
        gru_persistent<<<512, 256, 0, stream>>>(x, Wh, vp, b_r, b_z, b_c,
                                                hbuf, hb16, rh16, flags);
        fc_kernel<<<128, 256, 0, stream>>>(hbuf, W_fc, b_fc, (float*)d_out);
    } else {
        short* Wt_rz  = (short*)(ws);
        short* Wt_c   = (short*)(ws + 6291456);
        float* hbuf   = (float*)(ws + 9437184);
        short* hbf16  = (short*)(ws + 11534336);
        short* rhbf16 = (short*)(ws + 12582912);
        float* zbuf   = (float*)(ws + 13631488);

        prep_fb<<<18432, 256, 0, stream>>>(W_r, W_z, W_c, Wt_rz, Wt_c, hbuf, hbf16);
        for (int t = 0; t < T_; ++t) {
            gru_gemm<0><<<dim3(8, 32), 256, 0, stream>>>(
                x, emb, Wt_rz, hbf16, b_r, b_z, hbuf, zbuf, rhbf16, nullptr, nullptr, t);
            gru_gemm<1><<<dim3(8, 16), 256, 0, stream>>>(
                x, emb, Wt_c, rhbf16, b_c, nullptr, hbuf, zbuf, nullptr, hbuf, hbf16, t);
        }
        fc_kernel<<<128, 256, 0, stream>>>(hbuf, W_fc, b_fc, (float*)d_out);
    }
}

// Round 16
// 5264.181 us; speedup vs baseline: 1.1284x; 1.0018x over previous
//
#include <hip/hip_runtime.h>
#include <hip/hip_bf16.h>

#define B_ 512
#define T_ 256
#define E_ 512
#define H_ 1024
#define K_ 1536

typedef __attribute__((ext_vector_type(4))) float f32x4;
typedef __attribute__((ext_vector_type(8))) short s16x8;
typedef __attribute__((ext_vector_type(4))) unsigned int u32x4;
typedef __attribute__((ext_vector_type(2))) unsigned int u32x2;

typedef unsigned int u32_g __attribute__((address_space(1)));
typedef unsigned int u32_l __attribute__((address_space(3)));

static __device__ __forceinline__ void gload16(const void* g, void* l) {
    __builtin_amdgcn_global_load_lds((const u32_g*)g, (u32_l*)l, 16, 0, 0);
}
// coherent variant: aux=16 == CPol SC1 on gfx940/950 (agent-scope, L3)
static __device__ __forceinline__ void gload16sc(const void* g, void* l) {
    __builtin_amdgcn_global_load_lds((const u32_g*)g, (u32_l*)l, 16, 0, 16);
}

static __device__ __forceinline__ short f2b(float f) {
    union { float f; unsigned u; } v; v.f = f;
    unsigned r = v.u + 0x7FFFu + ((v.u >> 16) & 1u);   // RNE
    return (short)(r >> 16);
}
static __device__ __forceinline__ float bf2f(short s) {
    union { unsigned u; float f; } v; v.u = ((unsigned)(unsigned short)s) << 16;
    return v.f;
}
static __device__ __forceinline__ float sigmoidf_(float v) {
    return 1.f / (1.f + expf(-v));
}

#define WAITV(n) asm volatile("s_waitcnt vmcnt(" #n ")" ::: "memory")
#define WAITL    asm volatile("s_waitcnt lgkmcnt(0)" ::: "memory")
#define SB0 __builtin_amdgcn_sched_barrier(0)

// agent-coherent (L3) async loads/stores; pair with WAITV
static __device__ __forceinline__ u32x4 load16sc(const short* p) {
    u32x4 r;
    asm volatile("global_load_dwordx4 %0, %1, off sc1" : "=v"(r) : "v"(p));
    return r;
}
static __device__ __forceinline__ u32x2 load8sc(const short* p) {
    u32x2 r;
    asm volatile("global_load_dwordx2 %0, %1, off sc1" : "=v"(r) : "v"(p));
    return r;
}
static __device__ __forceinline__ void store2sc(const short* p, unsigned v) {
    asm volatile("global_store_short %0, %1, off sc1" :: "v"(p), "v"(v) : "memory");
}

// swizzled fragment read: 128-short rows (16 segs of 16B); logical seg s at
// physical s ^ (row&7)
#define FR(buf, row, k) \
    (*(const s16x8*)&(buf)[(row) * 128 + ((((k) >> 3) ^ ((row) & 7)) << 3)])

// ===========================================================================
// FAST PATH
// ===========================================================================

__global__ __launch_bounds__(256) void prep_fast(
    const float* __restrict__ W_r, const float* __restrict__ W_z,
    const float* __restrict__ W_c, const float* __restrict__ emb,
    short* __restrict__ We, short* __restrict__ Wh, short* __restrict__ embb,
    float* __restrict__ hbuf, short* __restrict__ hb16, unsigned* __restrict__ flags)
{
    const int NW = 3072 * 1536;
    const int NE = 50048 * 512;
    const int NH = 512 * 1024;
    const int NF = 8192;
    const int total = NW + NE + NH + NF;
    for (int idx = blockIdx.x * 256 + threadIdx.x; idx < total; idx += gridDim.x * 256) {
        if (idx < NW) {
            int n = idx / 1536, k = idx - n * 1536;
            const float* W = n < 1024 ? W_r : (n < 2048 ? W_z : W_c);
            float v = W[(size_t)k * 1024 + (n & 1023)];
            if (k < 512) We[(size_t)n * 512 + k] = f2b(v);
            else         Wh[(size_t)n * 1024 + (k - 512)] = f2b(v);
        } else if (idx < NW + NE) {
            int e = idx - NW; int row = e >> 9;
            embb[e] = row < 50000 ? f2b(emb[e]) : (short)0;
        } else if (idx < NW + NE + NH) {
            int h = idx - NW - NE;
            hbuf[h] = 0.f; hb16[h] = 0;
        } else {
            flags[idx - NW - NE - NH] = 0u;
        }
    }
}

__global__ __launch_bounds__(256) void vproj_gemm(
    const short* __restrict__ embb, const short* __restrict__ We,
    short* __restrict__ vp)
{
    __shared__ short As[128 * 64];
    __shared__ short Bs[128 * 64];
    const int tid = threadIdx.x, lane = tid & 63, w = tid >> 6;
    const int wm = (w >> 1) * 64, wn = (w & 1) * 64;
    const int m0 = blockIdx.x * 128, n0 = blockIdx.y * 128;
    f32x4 acc[4][4] = {};
    for (int kc = 0; kc < 8; ++kc) {
        int k0 = kc * 64;
        #pragma unroll
        for (int ii = 0; ii < 4; ++ii) {
            int i = w * 4 + ii;
            int row = i * 8 + (lane >> 3), kk = (lane & 7) * 8;
            gload16(embb + (size_t)(m0 + row) * 512 + k0 + kk, As + i * 512);
            gload16(We   + (size_t)(n0 + row) * 512 + k0 + kk, Bs + i * 512);
        }
        __syncthreads();
        #pragma unroll
        for (int kk = 0; kk < 64; kk += 32) {
            s16x8 a[4], b[4];
            #pragma unroll
            for (int f = 0; f < 4; ++f) {
                a[f] = *(const s16x8*)&As[(wm + f * 16 + (lane & 15)) * 64 + kk + (lane >> 4) * 8];
                b[f] = *(const s16x8*)&Bs[(wn + f * 16 + (lane & 15)) * 64 + kk + (lane >> 4) * 8];
            }
            #pragma unroll
            for (int fm = 0; fm < 4; ++fm)
            #pragma unroll
            for (int fn = 0; fn < 4; ++fn)
                acc[fm][fn] = __builtin_amdgcn_mfma_f32_16x16x32_bf16(a[fm], b[fn], acc[fm][fn], 0, 0, 0);
        }
        __syncthreads();
    }
    #pragma unroll
    for (int fm = 0; fm < 4; ++fm)
    #pragma unroll
    for (int fn = 0; fn < 4; ++fn)
    #pragma unroll
    for (int r = 0; r < 4; ++r) {
        int row = m0 + wm + fm * 16 + (lane >> 4) * 4 + r;
        int col = n0 + wn + fn * 16 + (lane & 15);
        vp[(size_t)row * 3072 + col] = f2b(acc[fm][fn][r]);
    }
}

// group barrier: relaxed agent atomics (sc1 ld/st, no wbl2/inv). WAITV(0)
// drains this wave's sc1 state stores first. First poll check without sleep;
// bounded spin failsafe.
static __device__ __forceinline__ void groupbar2(unsigned* gf, int member, unsigned gen) {
    WAITV(0);
    __syncthreads();
    if (threadIdx.x == 0) {
        __hip_atomic_store(&gf[member * 16], gen,
                           __ATOMIC_RELAXED, __HIP_MEMORY_SCOPE_AGENT);
    }
    if (threadIdx.x < 32) {
        unsigned v = __hip_atomic_load(&gf[threadIdx.x * 16],
                                       __ATOMIC_RELAXED, __HIP_MEMORY_SCOPE_AGENT);
        int spins = 0;
        while (v < gen) {
            __builtin_amdgcn_s_sleep(1);
            v = __hip_atomic_load(&gf[threadIdx.x * 16],
                                  __ATOMIC_RELAXED, __HIP_MEMORY_SCOPE_AGENT);
            if (++spins > (1 << 18)) break;   // failsafe: fail, don't wedge
        }
    }
    __syncthreads();
}

// xp gather; for PH2 result packed into .x/.y
template<int PH>
static __device__ __forceinline__ u32x4 gather_xp(const short* vp, int xv, int n) {
    const int part = threadIdx.x & 7;
    u32x4 r = {};
    if constexpr (PH == 1) {
        int col = (part < 4) ? (n * 32 + part * 8) : (1024 + n * 32 + (part - 4) * 8);
        r = load16sc(vp + (size_t)xv * 3072 + col);
    } else {
        u32x2 t2 = load8sc(vp + (size_t)xv * 3072 + 2048 + n * 32 + part * 4);
        r.x = t2.x; r.y = t2.y;
    }
    return r;
}

// ---------------------------------------------------------------------------
// one phase of one step. PH=1: rz (A=hb16, B rows = Wr[n*32..]+Wz[1024+n*32..],
// out: r*h -> rh16 (sc1), z -> zL). PH=2: cand (A=rh16, B rows = Wc[2048+n*32..],
// out: h' -> h_reg/hb16/hL).
// Tile: 32 (rows) x (PH==1 ? 64 : 32) cols, K=1024 in 8 chunks of 128.
// BOTH operands staged via global_load_lds (A with aux=16 = SC1 coherent).
// A triple-buffered (2-ahead), B double-buffered (1-ahead, L2-hot).
// xp pre-gathered at step start (phase2's xp completes under phase1's k-loop).
// ---------------------------------------------------------------------------
template<int PH>
static __device__ __forceinline__ void phaseX(
    const short* __restrict__ Ab,    // state rows base (+g*32*1024)
    const short* __restrict__ Wh,
    int g, int n, int t, u32x4 xp,
    short* AL, short* BL, short* XpL, float* zL, short* hL,
    const float* br, const float* bz, float bc,   // per-thread hoisted biases
    short* __restrict__ rh16, short* __restrict__ hb16,
    float* __restrict__ hbuf, f32x4& h_reg)
{
    const int tid = threadIdx.x, lane = tid & 63, w = tid >> 6;
    const int wm = (w >> 1) * 16;
    const int wn = (PH == 1) ? (w & 1) * 32 : (w & 1) * 16;
    constexpr int BROWS = (PH == 1) ? 64 : 32;      // B panel rows
    constexpr int BJ    = (PH == 1) ? 4 : 2;        // 16B segs per thread per B chunk
    constexpr int BUFSZ = BROWS * 128;              // shorts per B buffer

    // ---- staging helpers (both direct-to-LDS) ----
    auto issueA = [&](int c, int buf) {   // coherent (sc1) A chunk: 2 gloads
        #pragma unroll
        for (int j = 0; j < 2; ++j) {
            int sid = j * 256 + tid, row = sid >> 4, sg = (sid & 15) ^ (row & 7);
            gload16sc(Ab + (size_t)row * 1024 + c * 128 + sg * 8,
                      AL + buf * 4096 + (j * 256 + w * 64) * 8);
        }
    };
    auto issueB = [&](int c, int buf) {   // plain (L2-hot) B chunk
        #pragma unroll
        for (int j = 0; j < BJ; ++j) {
            int sid = j * 256 + tid, row = sid >> 4, sg = (sid & 15) ^ (row & 7);
            int grow;
            if constexpr (PH == 1) grow = (row < 32) ? (n * 32 + row) : (1024 + n * 32 + row - 32);
            else                   grow = 2048 + n * 32 + row;
            gload16(Wh + (size_t)grow * 1024 + c * 128 + sg * 8,
                    BL + buf * BUFSZ + (j * 256 + w * 64) * 8);
        }
    };

    // ---- prologue: B0 (1-ahead baseline), A0+A1 (2-ahead); xp pre-gathered ----
    issueB(0, 0);
    issueA(0, 0);
    issueA(1, 1);
    WAITV(2);   // (any older xp gathers), B0, A0 done; A1 outstanding
    SB0;
    {   // xp regs -> LDS
        int row = tid >> 3, part = tid & 7;
        if constexpr (PH == 1) {
            int dst = (part < 4) ? part * 8 : (32 + (part - 4) * 8);
            *(u32x4*)&XpL[row * 64 + dst] = xp;
        } else {
            u32x2 v2; v2.x = xp.x; v2.y = xp.y;
            *(u32x2*)&XpL[row * 32 + part * 4] = v2;
        }
    }
    WAITL;
    __builtin_amdgcn_s_barrier();
    SB0;

    // ---- k-loop: 8 chunks of 128; issue B(kc+1) then A(kc+2); gate WAITV(2) ----
    f32x4 acc[2] = {};
    #pragma unroll
    for (int kc = 0; kc < 8; ++kc) {
        if (kc < 7) issueB(kc + 1, (kc + 1) & 1);
        if (kc < 6) issueA(kc + 2, (kc + 2) % 3);
        const short* Ac = AL + (kc % 3) * 4096;
        const short* Bc = BL + (kc & 1) * BUFSZ;
        __builtin_amdgcn_s_setprio(1);          // T5: favor MFMA-phase waves
        #pragma unroll
        for (int ks = 0; ks < 4; ++ks) {
            const int kf = ks * 32 + (lane >> 4) * 8;
            s16x8 a = FR(Ac, wm + (lane & 15), kf);
            if constexpr (PH == 1) {
                s16x8 b0 = FR(Bc, wn + (lane & 15), kf);
                s16x8 b1 = FR(Bc, wn + 16 + (lane & 15), kf);
                acc[0] = __builtin_amdgcn_mfma_f32_16x16x32_bf16(a, b0, acc[0], 0, 0, 0);
                acc[1] = __builtin_amdgcn_mfma_f32_16x16x32_bf16(a, b1, acc[1], 0, 0, 0);
            } else {
                s16x8 b0 = FR(Bc, wn + (lane & 15), kf);
                acc[0] = __builtin_amdgcn_mfma_f32_16x16x32_bf16(a, b0, acc[0], 0, 0, 0);
            }
        }
        __builtin_amdgcn_s_setprio(0);
        if (kc < 7) {
            // need B(kc+1)+A(kc+1) landed; A(kc+2) (2 loads) may stay in flight
            if (kc < 6) { WAITV(2); } else { WAITV(0); }
            SB0;
            __builtin_amdgcn_s_barrier();
            SB0;
        }
    }

    // ---- epilogue ----
    const int rl0 = wm + (lane >> 4) * 4;
    if constexpr (PH == 1) {
        if ((w & 1) == 0) {   // r waves: global cols n*32 + (fn*16 + lane&15)
            #pragma unroll
            for (int fn = 0; fn < 2; ++fn) {
                int cl = fn * 16 + (lane & 15);
                #pragma unroll
                for (int ri = 0; ri < 4; ++ri) {
                    int rl = rl0 + ri;
                    float v = acc[fn][ri] + bf2f(XpL[rl * 64 + cl]) + br[fn];
                    float rr = sigmoidf_(v);
                    float hv = bf2f(hL[rl * 32 + cl]);
                    store2sc(rh16 + (size_t)(g * 32 + rl) * 1024 + n * 32 + cl,
                             (unsigned)(unsigned short)f2b(rr * hv));
                }
            }
        } else {              // z waves -> zL
            #pragma unroll
            for (int fn = 0; fn < 2; ++fn) {
                int zc = fn * 16 + (lane & 15);
                #pragma unroll
                for (int ri = 0; ri < 4; ++ri) {
                    int rl = rl0 + ri;
                    float v = acc[fn][ri] + bf2f(XpL[rl * 64 + 32 + zc]) + bz[fn];
                    zL[rl * 32 + zc] = sigmoidf_(v);
                }
            }
        }
    } else {
        int cl2 = wn + (lane & 15);
        #pragma unroll
        for (int ri = 0; ri < 4; ++ri) {
            int rl = rl0 + ri;
            float v = acc[0][ri] + bf2f(XpL[rl * 32 + cl2]) + bc;
            float c = tanhf(v);
            float zv = zL[rl * 32 + cl2];
            float h = h_reg[ri];
            float hn = h + zv * (c - h);
            h_reg[ri] = hn;
            short hb = f2b(hn);
            store2sc(hb16 + (size_t)(g * 32 + rl) * 1024 + n * 32 + cl2,
                     (unsigned)(unsigned short)hb);
            hL[rl * 32 + cl2] = hb;
            if (t == T_ - 1)
                hbuf[(size_t)(g * 32 + rl) * 1024 + n * 32 + cl2] = hn;
        }
    }
}

__global__ __launch_bounds__(256, 2) void gru_persistent(
    const int* __restrict__ x, const short* __restrict__ Wh,
    const short* __restrict__ vp,
    const float* __restrict__ b_r, const float* __restrict__ b_z,
    const float* __restrict__ b_c,
    float* __restrict__ hbuf, short* __restrict__ hb16,
    short* __restrict__ rh16, unsigned* __restrict__ flags)
{
    __shared__ short AL[3 * 4096];    // 24 KB  A triple-buffer (32x128)
    __shared__ short BL[2 * 8192];    // 32 KB  B double-buffer (64x128 / 32x128)
    __shared__ short XpL[2048];       // 4 KB   x-projection tile
    __shared__ float zL[1024];        // 4 KB   z (f32), phase1 -> phase2
    __shared__ short hL[1024];        // 2 KB   own h bf16 tile
    __shared__ int xidxL[32];

    const int bid = blockIdx.x;
    const int g = bid >> 5, n = bid & 31;    // 16 groups (32 batch rows) x 32 members
    unsigned* gf = flags + g * 512;

    const int tid = threadIdx.x, lane = tid & 63, w = tid >> 6;
    const int wm = (w >> 1) * 16, wn2 = (w & 1) * 16;

    // hoist per-thread biases
    float br[2], bz[2], bc;
    #pragma unroll
    for (int fn = 0; fn < 2; ++fn) {
        br[fn] = b_r[n * 32 + fn * 16 + (lane & 15)];
        bz[fn] = b_z[n * 32 + fn * 16 + (lane & 15)];
    }
    bc = b_c[n * 32 + wn2 + (lane & 15)];

    // init: h = 0 (regs + own hL tile)
    f32x4 h_reg = {0.f, 0.f, 0.f, 0.f};
    #pragma unroll
    for (int ri = 0; ri < 4; ++ri)
        hL[(wm + (lane >> 4) * 4 + ri) * 32 + wn2 + (lane & 15)] = 0;

    for (int t = 0; t < T_; ++t) {
        if (tid < 32) xidxL[tid] = x[(g * 32 + tid) * T_ + t];
        __syncthreads();
        // issue BOTH xp gathers now: xp2 completes under phase1's k-loop,
        // removing the HBM gather from phase2's prologue gate entirely.
        const int xv = xidxL[tid >> 3];
        u32x4 xp1 = gather_xp<1>(vp, xv, n);
        u32x4 xp2 = gather_xp<2>(vp, xv, n);
        SB0;
        phaseX<1>(hb16 + (size_t)(g * 32) * 1024, Wh, g, n, t, xp1,
                  AL, BL, XpL, zL, hL, br, bz, bc, rh16, hb16, hbuf, h_reg);
        groupbar2(gf, n, 2 * t + 1);
        phaseX<2>(rh16 + (size_t)(g * 32) * 1024, Wh, g, n, t, xp2,
                  AL, BL, XpL, zL, hL, br, bz, bc, rh16, hb16, hbuf, h_reg);
        if (t < T_ - 1) groupbar2(gf, n, 2 * t + 2);
    }
}

__global__ __launch_bounds__(256) void fc_kernel(
    const float* __restrict__ h, const float* __restrict__ Wfc,
    const float* __restrict__ bfc, float* __restrict__ out)
{
    int gw   = (blockIdx.x * 256 + threadIdx.x) >> 6;
    int lane = threadIdx.x & 63;
    if (gw >= B_) return;
    float s = 0.f;
    for (int j = lane; j < H_; j += 64) s += h[(size_t)gw * H_ + j] * Wfc[j];
    #pragma unroll
    for (int off = 32; off; off >>= 1) s += __shfl_down(s, off);
    if (lane == 0) out[gw] = sigmoidf_(s + bfc[0]);
}

// ===========================================================================
// FALLBACK PATH (round-1, used when ws_size is too small)
// ===========================================================================
__global__ __launch_bounds__(256) void prep_fb(
    const float* __restrict__ W_r, const float* __restrict__ W_z,
    const float* __restrict__ W_c,
    short* __restrict__ Wt_rz, short* __restrict__ Wt_c,
    float* __restrict__ hbuf, short* __restrict__ hbf16)
{
    const int PER = H_ * K_;
    int idx = blockIdx.x * 256 + threadIdx.x;
    if (idx < PER * 3) {
        int mm = idx / PER, rem = idx - mm * PER;
        int n = rem / K_, k = rem - n * K_;
        if (mm == 0)      Wt_rz[(size_t)n * K_ + k]        = f2b(W_r[(size_t)k * H_ + n]);
        else if (mm == 1) Wt_rz[(size_t)(H_ + n) * K_ + k] = f2b(W_z[(size_t)k * H_ + n]);
        else              Wt_c[(size_t)n * K_ + k]         = f2b(W_c[(size_t)k * H_ + n]);
    }
    if (idx < B_ * H_) { hbuf[idx] = 0.f; hbf16[idx] = 0; }
}

template<int MODE>
__global__ __launch_bounds__(256) void gru_gemm(
    const int* __restrict__ x, const float* __restrict__ emb,
    const short* __restrict__ Wt, const short* __restrict__ hpart,
    const float* __restrict__ bias0, const float* __restrict__ bias1,
    const float* __restrict__ hbuf, float* __restrict__ zbuf,
    short* __restrict__ rh_out, float* __restrict__ h_out,
    short* __restrict__ hb_out, int t)
{
    __shared__ short As2[64][72];
    __shared__ short Bs2[64][72];
    __shared__ int xidx2[64];
    const int tid = threadIdx.x;
    const int bm = blockIdx.x, bn = blockIdx.y;
    if (tid < 64) xidx2[tid] = x[(bm * 64 + tid) * T_ + t];
    f32x4 acc[2][2] = {};
    const int m  = tid >> 2;
    const int ks = (tid & 3) * 16;
    const int w  = tid >> 6, lane = tid & 63;
    const int wm = (w >> 1) * 32, wn = (w & 1) * 32;
    const int lr = lane & 15, lk = (lane >> 4) * 8;
    __syncthreads();
    for (int kt = 0; kt < 24; ++kt) {
        const int k0 = kt * 64;
        if (k0 < E_) {
            const int row = xidx2[m];
            const float4* src = (const float4*)&emb[(size_t)row * E_ + k0 + ks];
            short tmp[16];
            #pragma unroll
            for (int v = 0; v < 4; ++v) {
                float4 f = src[v];
                tmp[v*4+0] = f2b(f.x); tmp[v*4+1] = f2b(f.y);
                tmp[v*4+2] = f2b(f.z); tmp[v*4+3] = f2b(f.w);
            }
            *(s16x8*)&As2[m][ks]     = *(const s16x8*)&tmp[0];
            *(s16x8*)&As2[m][ks + 8] = *(const s16x8*)&tmp[8];
        } else {
            const s16x8* src = (const s16x8*)&hpart[(size_t)(bm*64 + m) * H_ + (k0 - E_ + ks)];
            *(s16x8*)&As2[m][ks]     = src[0];
            *(s16x8*)&As2[m][ks + 8] = src[1];
        }
        {
            const s16x8* src = (const s16x8*)&Wt[(size_t)(bn*64 + m) * K_ + k0 + ks];
            *(s16x8*)&Bs2[m][ks]     = src[0];
            *(s16x8*)&Bs2[m][ks + 8] = src[1];
        }
        __syncthreads();
        #pragma unroll
        for (int kk = 0; kk < 64; kk += 32) {
            s16x8 a0 = *(const s16x8*)&As2[wm      + lr][kk + lk];
            s16x8 a1 = *(const s16x8*)&As2[wm + 16 + lr][kk + lk];
            s16x8 b0 = *(const s16x8*)&Bs2[wn      + lr][kk + lk];
            s16x8 b1 = *(const s16x8*)&Bs2[wn + 16 + lr][kk + lk];
            acc[0][0] = __builtin_amdgcn_mfma_f32_16x16x32_bf16(a0, b0, acc[0][0], 0, 0, 0);
            acc[0][1] = __builtin_amdgcn_mfma_f32_16x16x32_bf16(a0, b1, acc[0][1], 0, 0, 0);
            acc[1][0] = __builtin_amdgcn_mfma_f32_16x16x32_bf16(a1, b0, acc[1][0], 0, 0, 0);
            acc[1][1] = __builtin_amdgcn_mfma_f32_16x16x32_bf16(a1, b1, acc[1][1], 0, 0, 0);
        }
        __syncthreads();
    }
    #pragma unroll
    for (int fm = 0; fm < 2; ++fm)
    #pragma unroll
    for (int fn = 0; fn < 2; ++fn)
    #pragma unroll
    for (int r = 0; r < 4; ++r) {
        const int row = bm * 64 + wm + fm * 16 + ((lane >> 4) * 4 + r);
        const int n   = bn * 64 + wn + fn * 16 + (lane & 15);
        float v = acc[fm][fn][r];
        if (MODE == 0) {
            if (n < H_) {
                float rr = sigmoidf_(v + bias0[n]);
                size_t idx = (size_t)row * H_ + n;
                rh_out[idx] = f2b(rr * hbuf[idx]);
            } else {
                int nz = n - H_;
                zbuf[(size_t)row * H_ + nz] = sigmoidf_(v + bias1[nz]);
            }
        } else {
            float ht = tanhf(v + bias0[n]);
            size_t idx = (size_t)row * H_ + n;
            float h = hbuf[idx], z = zbuf[idx];
            float hn = (1.f - z) * h + z * ht;
            h_out[idx]  = hn;
            hb_out[idx] = f2b(hn);
        }
    }
}

// ===========================================================================
extern "C" void kernel_launch(void* const* d_in, const int* in_sizes, int n_in,
                              void* d_out, int out_size, void* d_ws, size_t ws_size,
                              hipStream_t stream) {
    const int*   x    = (const int*)  d_in[0];
    const float* emb  = (const float*)d_in[1];
    const float* W_r  = (const float*)d_in[2];
    const float* b_r  = (const float*)d_in[3];
    const float* W_z  = (const float*)d_in[4];
    const float* b_z  = (const float*)d_in[5];
    const float* W_c  = (const float*)d_in[6];
    const float* b_c  = (const float*)d_in[7];
    const float* W_fc = (const float*)d_in[8];
    const float* b_fc = (const float*)d_in[9];

    char* ws = (char*)d_ws;
    const size_t NEED = 374489088ULL;

    if (ws_size >= NEED) {
        short*    We    = (short*)(ws);
        short*    Wh    = (short*)(ws + 3145728);
        short*    embb  = (short*)(ws + 9437184);
        short*    vp    = (short*)(ws + 60686336);
        float*    hbuf  = (float*)(ws + 368181248);
        short*    hb16  = (short*)(ws + 370278400);
        short*    rh16  = (short*)(ws + 371326976);
        unsigned* flags = (unsigned*)(ws + 372375552);

        prep_fast<<<2048, 256, 0, stream>>>(W_r, W_z, W_c, emb, We, Wh, embb, hbuf, hb16, flags);
        vproj_gemm<<<dim3(391, 24), 256, 0, stream>>>(embb, We, vp);
        gru_persistent<<<512, 256, 0, stream>>>(x, Wh, vp, b_r, b_z, b_c,
                                                hbuf, hb16, rh16, flags);
        fc_kernel<<<128, 256, 0, stream>>>(hbuf, W_fc, b_fc, (float*)d_out);
    } else {
        short* Wt_rz  = (short*)(ws);
        short* Wt_c   = (short*)(ws + 6291456);
        float* hbuf   = (float*)(ws + 9437184);
        short* hbf16  = (short*)(ws + 11534336);
        short* rhbf16 = (short*)(ws + 12582912);
        float* zbuf   = (float*)(ws + 13631488);

        prep_fb<<<18432, 256, 0, stream>>>(W_r, W_z, W_c, Wt_rz, Wt_c, hbuf, hbf16);
        for (int t = 0; t < T_; ++t) {
            gru_gemm<0><<<dim3(8, 32), 256, 0, stream>>>(
                x, emb, Wt_rz, hbf16, b_r, b_z, hbuf, zbuf, rhbf16, nullptr, nullptr, t);
            gru_gemm<1><<<dim3(8, 16), 256, 0, stream>>>(
                x, emb, Wt_c, rhbf16, b_c, nullptr, hbuf, zbuf, nullptr, hbuf, hbf16, t);
        }
        fc_kernel<<<128, 256, 0, stream>>>(hbuf, W_fc, b_fc, (float*)d_out);
    }
}